// Round 1
// baseline (12468.251 us; speedup 1.0000x reference)
//
#include <hip/hip_runtime.h>
#include <hip/hip_bf16.h>
#include <stdint.h>

// SNN LIF multi-layer, B=16384, D_IN=N=512, L=3, T=32 (T hardcoded: device
// scalar can't be read under graph capture; it's a constant of the problem).
//
// Round 1: correctness-first f32 SGEMM with fused LIF epilogue.
//  - spikes s stored as bf16 (values {0,1} exact)
//  - a[0], a[2] accumulated directly in d_out, scaled in-place at the end
//  - 97 sequential launches (dependencies are real: layer i feeds layer i+1,
//    layer L-1 feeds layer 0 next step)

#define B_SZ 16384
#define N_SZ 512
#define K_SZ 512
#define T_STEPS 32
#define LEAKY 0.9f

#define BM 128
#define BN 128
#define BK 16
#define TM 8
#define TN 8
#define PAD 4

union U32F { uint32_t u; float f; };
__device__ inline float bf16_to_f32(uint16_t h) {
    U32F v; v.u = ((uint32_t)h) << 16; return v.f;
}

// AMODE: 0 = no accumulator, 1 = a := s (init), 2 = a := a*LEAKY + s
template<bool A_BF16, int AMODE, bool ADD_U, bool ADD_X1, bool STORE_C>
__global__ __launch_bounds__(256, 2)
void gemm_lif(const void* __restrict__ Aptr,     // [B,K] f32 or bf16
              const float* __restrict__ W,       // [N,K] row-major
              const float* __restrict__ bias,    // [N]
              const float* __restrict__ u_prev,  // [B,N] (ADD_U)
              const float* __restrict__ x1,      // [B,N] (ADD_X1)
              float* __restrict__ u_out,         // [B,N]
              uint16_t* __restrict__ s_out,      // [B,N] bf16 bits
              float* __restrict__ a_ptr,         // [B,N] (AMODE!=0)
              float* __restrict__ c_out)         // [B,N] (STORE_C: pre-LIF)
{
    __shared__ float As[BK][BM + PAD];
    __shared__ float Bs[BK][BN + PAD];

    const int tid = threadIdx.x;
    const int tx = tid & 15;   // n dir, 0..15
    const int ty = tid >> 4;   // m dir, 0..15
    const int m0 = blockIdx.y * BM;
    const int n0 = blockIdx.x * BN;

    float acc[TM][TN];
    #pragma unroll
    for (int i = 0; i < TM; ++i)
        #pragma unroll
        for (int j = 0; j < TN; ++j) acc[i][j] = 0.f;

    const int lr = tid >> 2;        // 0..63 (row within tile)
    const int lc = (tid & 3) * 4;   // 0,4,8,12 (k within tile)

    for (int k0 = 0; k0 < K_SZ; k0 += BK) {
        if (A_BF16) {
            const uint16_t* A = (const uint16_t*)Aptr;
            #pragma unroll
            for (int h = 0; h < 2; ++h) {
                const int r = lr + h * 64;
                const ushort4 v = *(const ushort4*)(A + (size_t)(m0 + r) * K_SZ + k0 + lc);
                As[lc + 0][r] = bf16_to_f32(v.x);
                As[lc + 1][r] = bf16_to_f32(v.y);
                As[lc + 2][r] = bf16_to_f32(v.z);
                As[lc + 3][r] = bf16_to_f32(v.w);
            }
        } else {
            const float* A = (const float*)Aptr;
            #pragma unroll
            for (int h = 0; h < 2; ++h) {
                const int r = lr + h * 64;
                const float4 v = *(const float4*)(A + (size_t)(m0 + r) * K_SZ + k0 + lc);
                As[lc + 0][r] = v.x;
                As[lc + 1][r] = v.y;
                As[lc + 2][r] = v.z;
                As[lc + 3][r] = v.w;
            }
        }
        #pragma unroll
        for (int h = 0; h < 2; ++h) {
            const int r = lr + h * 64;
            const float4 v = *(const float4*)(W + (size_t)(n0 + r) * K_SZ + k0 + lc);
            Bs[lc + 0][r] = v.x;
            Bs[lc + 1][r] = v.y;
            Bs[lc + 2][r] = v.z;
            Bs[lc + 3][r] = v.w;
        }
        __syncthreads();

        #pragma unroll
        for (int kk = 0; kk < BK; ++kk) {
            float av[TM], bv[TN];
            #pragma unroll
            for (int i = 0; i < TM; ++i) av[i] = As[kk][ty * TM + i];
            #pragma unroll
            for (int j = 0; j < TN; ++j) bv[j] = Bs[kk][tx * TN + j];
            #pragma unroll
            for (int i = 0; i < TM; ++i)
                #pragma unroll
                for (int j = 0; j < TN; ++j)
                    acc[i][j] = fmaf(av[i], bv[j], acc[i][j]);
        }
        __syncthreads();
    }

    // ---- fused LIF epilogue ----
    float bv[TN];
    #pragma unroll
    for (int j = 0; j < TN; ++j) bv[j] = bias[n0 + tx * TN + j];

    #pragma unroll
    for (int i = 0; i < TM; ++i) {
        const int b = m0 + ty * TM + i;
        const size_t row = (size_t)b * N_SZ + n0 + tx * TN;
        float v[TN];
        #pragma unroll
        for (int j = 0; j < TN; ++j) v[j] = acc[i][j] + bv[j];
        if (ADD_U) {
            #pragma unroll
            for (int j = 0; j < TN; ++j) v[j] += u_prev[row + j];
        }
        if (ADD_X1) {
            #pragma unroll
            for (int j = 0; j < TN; ++j) v[j] += x1[row + j];
        }
        if (STORE_C) {
            #pragma unroll
            for (int j = 0; j < TN; ++j) c_out[row + j] = v[j];
        }
        #pragma unroll
        for (int j = 0; j < TN; ++j) {
            const float sv = (v[j] >= 1.0f) ? 1.0f : 0.0f;
            u_out[row + j] = (v[j] - 2.0f * sv) * LEAKY;
            s_out[row + j] = (v[j] >= 1.0f) ? (uint16_t)0x3F80 : (uint16_t)0;
            if (AMODE == 1)      a_ptr[row + j] = sv;
            else if (AMODE == 2) a_ptr[row + j] = a_ptr[row + j] * LEAKY + sv;
        }
    }
}

__global__ void scale_kernel(float* __restrict__ p, float inv, int n4) {
    int i = blockIdx.x * blockDim.x + threadIdx.x;
    const int stride = gridDim.x * blockDim.x;
    for (; i < n4; i += stride) {
        float4 v = ((float4*)p)[i];
        v.x *= inv; v.y *= inv; v.z *= inv; v.w *= inv;
        ((float4*)p)[i] = v;
    }
}

extern "C" void kernel_launch(void* const* d_in, const int* in_sizes, int n_in,
                              void* d_out, int out_size, void* d_ws, size_t ws_size,
                              hipStream_t stream) {
    const float* x  = (const float*)d_in[0];   // [B, 512]
    const float* Wx = (const float*)d_in[1];   // [512, 512]
    const float* bx = (const float*)d_in[2];   // [512]
    const float* Ws = (const float*)d_in[3];   // [3, 512, 512]
    const float* bs = (const float*)d_in[4];   // [3, 512]
    // d_in[5] = time_step (device scalar) -> hardcoded T_STEPS=32

    const size_t BNt = (size_t)B_SZ * N_SZ;
    const size_t NK  = (size_t)N_SZ * K_SZ;

    float*    u  = (float*)d_ws;                 // [3][B][N] f32
    uint16_t* s  = (uint16_t*)(u + 3 * BNt);     // [3][B][N] bf16
    float*    x1 = (float*)(s + 3 * BNt);        // [B][N] f32
    float*    a0 = (float*)d_out;                // [B][N]
    float*    a2 = a0 + BNt;                     // [B][N]

    float*    u0 = u;           float* u1 = u + BNt;  float* u2 = u + 2 * BNt;
    uint16_t* s0 = s;           uint16_t* s1 = s + BNt; uint16_t* s2 = s + 2 * BNt;

    dim3 grid(N_SZ / BN, B_SZ / BM);
    dim3 blk(256);

    // ---- t = 0 ----
    // layer 0: x1 = x@Wx.T + bx (stored); u0,s0 = lif(x1); a0 = s0
    gemm_lif<false, 1, false, false, true><<<grid, blk, 0, stream>>>(
        x, Wx, bx, nullptr, nullptr, u0, s0, a0, x1);
    // layer 1: u1,s1 = lif(s0@Ws[0].T + bs[0])
    gemm_lif<true, 0, false, false, false><<<grid, blk, 0, stream>>>(
        s0, Ws, bs, nullptr, nullptr, u1, s1, nullptr, nullptr);
    // layer 2: u2,s2 = lif(s1@Ws[1].T + bs[1]); a2 = s2
    gemm_lif<true, 1, false, false, false><<<grid, blk, 0, stream>>>(
        s1, Ws + NK, bs + N_SZ, nullptr, nullptr, u2, s2, a2, nullptr);

    // ---- t = 1 .. T-1 ----
    for (int t = 1; t < T_STEPS; ++t) {
        // layer 0: u0 += s2@Ws[2].T + bs[2] + x1 ; lif ; a0 = a0*LEAKY + s0
        gemm_lif<true, 2, true, true, false><<<grid, blk, 0, stream>>>(
            s2, Ws + 2 * NK, bs + 2 * N_SZ, u0, x1, u0, s0, a0, nullptr);
        // layer 1: u1 += s0@Ws[0].T + bs[0] ; lif
        gemm_lif<true, 0, true, false, false><<<grid, blk, 0, stream>>>(
            s0, Ws, bs, u1, nullptr, u1, s1, nullptr, nullptr);
        // layer 2: u2 += s1@Ws[1].T + bs[1] ; lif ; a2 = a2*LEAKY + s2
        gemm_lif<true, 2, true, false, false><<<grid, blk, 0, stream>>>(
            s1, Ws + NK, bs + N_SZ, u2, nullptr, u2, s2, a2, nullptr);
    }

    // ---- finalize: a /= (1 - 0.9^32)/0.1 ----
    double p = 1.0;
    for (int i = 0; i < T_STEPS; ++i) p *= 0.9;
    const float inv = (float)(1.0 / ((1.0 - p) / 0.1));
    scale_kernel<<<2048, blk, 0, stream>>>((float*)d_out, inv, (int)(2 * BNt / 4));
}